// Round 1
// baseline (445.552 us; speedup 1.0000x reference)
//
#include <hip/hip_runtime.h>
#include <stdint.h>

#define NB   4096
#define DIN  1024
#define DOUT 1024
#define NL   32
#define KPW  (DIN * NL)     // 32768
#define KTOT (KPW + 64)     // 32832 (pad: 32 bias cols + 32 zero cols)
#define BKT  64
#define NSPLIT 4            // split-K ways over 513 K-tiles: 129+128+128+128

typedef __attribute__((ext_vector_type(8))) short short8;          // 8 bf16 (A/B frag)
typedef __attribute__((ext_vector_type(8))) unsigned short ushort8;
typedef __attribute__((ext_vector_type(4))) float floatx4;         // C/D frag

// float -> bf16 bits, round-to-nearest-even (finite inputs only)
__device__ __forceinline__ unsigned short f2bf(float v) {
    uint32_t u = __float_as_uint(v);
    return (unsigned short)((u + 0x7FFFu + ((u >> 16) & 1u)) >> 16);
}

// two floats -> packed bf16x2 (RNE), low half = a (proven numerics, keep)
__device__ __forceinline__ uint32_t f2bf2(float a, float b) {
    uint32_t ua = __float_as_uint(a), ub = __float_as_uint(b);
    ua += 0x7FFFu + ((ua >> 16) & 1u);
    ub += 0x7FFFu + ((ub >> 16) & 1u);
    return __builtin_amdgcn_perm(ub, ua, 0x07060302u);  // {ub_hi16, ua_hi16}
}

// async global->LDS, 16B per lane; LDS dst = wave-uniform base + lane*16
__device__ __forceinline__ void async_ld16(const void* g, void* l) {
    __builtin_amdgcn_global_load_lds(
        (const __attribute__((address_space(1))) void*)g,
        (__attribute__((address_space(3))) void*)l, 16, 0, 0);
}

// ---------------------------------------------------------------------------
// Fused prep (unchanged from r6; ~44us, near its ~37us HBM roofline):
//   blocks [0,1024)    : pw fp32 (+pb) -> bf16 pwb row
//   blocks [1024,2048) : gating softmax, 4 rows/block -> g fp32
//   blocks [2048,2112) : zero d_out (harness poisons it 0xAA each replay)
// ---------------------------------------------------------------------------
__global__ __launch_bounds__(256) void prep_fused(
    const float* __restrict__ x, const float* __restrict__ gw,
    const float* __restrict__ gb, const float* __restrict__ pw,
    const float* __restrict__ pb, float* __restrict__ g,
    unsigned short* __restrict__ pwb, float* __restrict__ C)
{
    const int id = blockIdx.x;
    const int t  = threadIdx.x;

    if (id < DOUT) {
        const int o = id;
        const float* src = pw + (size_t)o * KPW;
        unsigned short* dst = pwb + (size_t)o * KTOT;
        #pragma unroll 2
        for (int s = 0; s < 16; ++s) {
            const int k = (s * 256 + t) * 8;
            const float4 a = *(const float4*)(src + k);
            const float4 c = *(const float4*)(src + k + 4);
            ushort8 o8;
            o8[0] = f2bf(a.x); o8[1] = f2bf(a.y); o8[2] = f2bf(a.z); o8[3] = f2bf(a.w);
            o8[4] = f2bf(c.x); o8[5] = f2bf(c.y); o8[6] = f2bf(c.z); o8[7] = f2bf(c.w);
            *(ushort8*)(dst + k) = o8;
        }
        if (t < 8) {   // tail: 32 bias cols + 32 zeros
            ushort8 o8;
            #pragma unroll
            for (int j = 0; j < 8; ++j) {
                const int l = t * 8 + j;
                o8[j] = (l < NL) ? f2bf(pb[(size_t)o * NL + l]) : (unsigned short)0;
            }
            *(ushort8*)(dst + KPW + t * 8) = o8;
        }
    } else if (id < DOUT + NB / 4) {
        const int wave = t >> 6;
        const int lane = t & 63;
        const int b = (id - DOUT) * 4 + wave;
        const int l = lane & 31;
        const int c = lane >> 5;
        const float* xrow = x + (size_t)b * DIN;
        float p0 = 0.f, p1 = 0.f, p2 = 0.f, p3 = 0.f;
        const int i0 = c * 512;
        #pragma unroll 2
        for (int j = 0; j < 512; j += 4) {
            const int i = i0 + j;
            p0 = fmaf(xrow[i + 0], gw[(i + 0) * NL + l], p0);
            p1 = fmaf(xrow[i + 1], gw[(i + 1) * NL + l], p1);
            p2 = fmaf(xrow[i + 2], gw[(i + 2) * NL + l], p2);
            p3 = fmaf(xrow[i + 3], gw[(i + 3) * NL + l], p3);
        }
        float p = (p0 + p1) + (p2 + p3);
        p += __shfl_xor(p, 32);
        const float logit = p + gb[l];
        float m = logit;
        for (int off = 16; off > 0; off >>= 1) m = fmaxf(m, __shfl_xor(m, off));
        const float e = __expf(logit - m);
        float s = e;
        for (int off = 16; off > 0; off >>= 1) s += __shfl_xor(s, off);
        if (lane < NL) g[(size_t)b * NL + l] = e / s;
    } else {
        const int zb = id - (DOUT + NB / 4);
        float4* dst = (float4*)C + (size_t)zb * (256 * 64) + t;
        const float4 z4 = {0.f, 0.f, 0.f, 0.f};
        #pragma unroll 4
        for (int s = 0; s < 64; ++s) dst[s * 256] = z4;
    }
}

// ---------------------------------------------------------------------------
// r7: 256x256-tile, 8-wave, 4-phase-per-K-tile counted-vmcnt GEMM (the
// documented T3+T4+T2+T5 structure; replaces the m97-class 128x128 kernel
// that plateaued at 886 TF). C[b,o] += sum_k y[b,k]*pwb[o,k], y built on the
// fly: y[b,i*32+l] = bf16(x[b,i]*g[b,l]); bias K-tile it=512 uses x==1.
//
//  - B: global_load_lds x4/tile into 3-deep rotating LDS buffer, issued 2
//    tiles ahead (2 loads P1 + 2 loads P2); vmcnt(2) once per tile, never 0.
//    Tail iterations re-stage the last tile into the dead buffer so the
//    per-wave vmcnt arithmetic is iteration-invariant.
//  - A: single 32KB buffer; reads in P1/P3, build(t+1) in P4 (after the
//    P3-end barrier = all readers done), drained by lgkmcnt(0) before the
//    P4-end barrier.
//  - Phases: {issue DMA || ds_read subtile ; s_barrier ; setprio(1) 16 MFMA
//    setprio(0) ; s_barrier}, quadrants q00,q01,q11,q10 so af/bf regs carry
//    across adjacent phases (frag regs: 32 A + 16 B; acc 128; ~220 total).
//  - XOR swizzle (r2 scheme) on both A-build writes and B DMA source; reads
//    use the matching involution.
//  - Grid 256 = 16 bm x 4 bn x 4 splitK, 1 block/CU; XCD decode puts the 16
//    bm-blocks of one (bn,z) on one XCD -> each 32KB B K-tile is fetched
//    once per L2 and hit 15x.
// ---------------------------------------------------------------------------
__global__ __launch_bounds__(512, 2) void gemm_8phase(
    const float* __restrict__ X,            // x [NB][DIN] fp32
    const float* __restrict__ G,            // g [NB][NL]  fp32
    const unsigned short* __restrict__ Bw,  // pwb [DOUT][KTOT] bf16
    float* __restrict__ C)                  // [NB][DOUT], pre-zeroed
{
    __shared__ __align__(16) unsigned short Ash[256 * BKT];     // 32 KB
    __shared__ __align__(16) unsigned short Bsh[3][256 * BKT];  // 96 KB

    const int t    = threadIdx.x;
    const int wave = t >> 6;
    const int lane = t & 63;

    // grid decode: XCD x gets combos {x, x+8} -> one bn panel, two z-windows
    const int bid   = blockIdx.x;
    const int xcd   = bid & 7;
    const int seq   = bid >> 3;                 // 0..31
    const int combo = xcd + 8 * (seq >> 4);     // 0..15 = (bn,z)
    const int bm    = (seq & 15) * 256;
    const int bn    = (combo & 3) * 256;
    const int z     = combo >> 2;               // 0..3
    const int it0   = z * 128 + (z ? 1 : 0);    // splits: 129+128+128+128
    const int it1   = (z + 1) * 128 + 1;

    // wave -> 128x64 output sub-tile
    const int wr   = wave >> 2;                 // 0..1
    const int wc   = wave & 3;                  // 0..3
    const int ml   = lane & 15;
    const int quad = lane >> 4;
    const int xm   = ml & 7;
    const int sw0  = (quad ^ xm) * 8;           // kk=0 chunk swizzle
    const int sw1  = ((4 + quad) ^ xm) * 8;     // kk=1

    // B staging: thread t stages row trow of each 64-row group, pre-swizzled src
    const int trow = t >> 3;                    // 0..63
    const unsigned short* Bg = Bw + (size_t)(bn + trow) * KTOT
                             + (((t & 7) ^ (trow & 7)) * 8);
    const int lbase = wave * 512;               // wave-uniform LDS stage base

    // A on-the-fly build: thread owns row r, leaves (t&1)*16..+15, both i0/i1
    const int r = t >> 1, rx = r & 7, lsel = (t & 1) * 2;
    const float* xp = X + (size_t)(bm + r) * DIN;
    unsigned short* Aw = Ash + r * BKT;

    float gq[16];
    {
        const float* gp = G + (size_t)(bm + r) * NL + (t & 1) * 16;
        #pragma unroll
        for (int q = 0; q < 4; ++q) {
            const float4 v = *(const float4*)(gp + q * 4);
            gq[q*4+0] = v.x; gq[q*4+1] = v.y; gq[q*4+2] = v.z; gq[q*4+3] = v.w;
        }
    }

    const unsigned short* aB = Ash + (wr * 128 + ml) * BKT;

    floatx4 acc[8][4] = {};
    short8 af[8], bf[4];
    float2 xv;

    auto buildA = [&](int T) {
        const bool inb = (T * 2) < DIN;
        const float xa = inb ? xv.x : 1.0f;     // i=1024: y-col = g (pairs pb)
        const float xb = inb ? xv.y : 0.0f;     // i=1025: zero pad
        #pragma unroll
        for (int ii = 0; ii < 2; ++ii) {
            const float xs = ii ? xb : xa;
            #pragma unroll
            for (int j = 0; j < 2; ++j) {
                uint4 v;
                v.x = f2bf2(xs * gq[j*8+0], xs * gq[j*8+1]);
                v.y = f2bf2(xs * gq[j*8+2], xs * gq[j*8+3]);
                v.z = f2bf2(xs * gq[j*8+4], xs * gq[j*8+5]);
                v.w = f2bf2(xs * gq[j*8+6], xs * gq[j*8+7]);
                const int c = ii * 4 + lsel + j;
                *(uint4*)(Aw + ((c ^ rx) * 8)) = v;
            }
        }
    };

    // ---- prologue: stage B(it0)->buf0, B(it0+1)->buf1; build A(it0) ----
    xv = *(const float2*)(xp + it0 * 2);
    {
        const unsigned short* s0 = Bg + (size_t)it0 * BKT;
        #pragma unroll
        for (int s = 0; s < 4; ++s)
            async_ld16(s0 + (size_t)s * 64 * KTOT, &Bsh[0][lbase + s * 4096]);
        const unsigned short* s1 = s0 + BKT;
        #pragma unroll
        for (int s = 0; s < 4; ++s)
            async_ld16(s1 + (size_t)s * 64 * KTOT, &Bsh[1][lbase + s * 4096]);
    }
    buildA(it0);
    // B(it0) landed (leave B(it0+1)'s 4 in flight) + A writes drained
    asm volatile("s_waitcnt vmcnt(4) lgkmcnt(0)" ::: "memory");
    __builtin_amdgcn_s_barrier();

    int pr = 0, ps = 2;   // read buf, stage buf ( = (tt+2)%3 = dead buf )
    for (int it = it0; it < it1; ++it) {
        const unsigned short* bB = Bsh[pr] + (wc * 64 + ml) * BKT;
        const int tf = (it + 2 < it1) ? (it + 2) : (it1 - 1);  // dummy at tail
        const unsigned short* sf = Bg + (size_t)tf * BKT;
        unsigned short* db = &Bsh[ps][lbase];

        // ---- P1: DMA h0 | x prefetch | read A(im0-3),B(in0-1) | q00 ----
        async_ld16(sf,                     db);
        async_ld16(sf + (size_t)64 * KTOT, db + 4096);
        xv = *(const float2*)(xp + (((it + 1) * 2 < DIN) ? (it + 1) * 2 : (DIN - 2)));
        #pragma unroll
        for (int im = 0; im < 4; ++im) {
            af[im*2+0] = *(const short8*)(aB + (im*16)*BKT + sw0);
            af[im*2+1] = *(const short8*)(aB + (im*16)*BKT + sw1);
        }
        #pragma unroll
        for (int in = 0; in < 2; ++in) {
            bf[in*2+0] = *(const short8*)(bB + (in*16)*BKT + sw0);
            bf[in*2+1] = *(const short8*)(bB + (in*16)*BKT + sw1);
        }
        __builtin_amdgcn_s_barrier();
        __builtin_amdgcn_s_setprio(1);
        #pragma unroll
        for (int im = 0; im < 4; ++im)
            #pragma unroll
            for (int in = 0; in < 2; ++in)
                #pragma unroll
                for (int kk = 0; kk < 2; ++kk)
                    acc[im][in] = __builtin_amdgcn_mfma_f32_16x16x32_bf16(
                        af[im*2+kk], bf[in*2+kk], acc[im][in], 0, 0, 0);
        __builtin_amdgcn_s_setprio(0);
        __builtin_amdgcn_s_barrier();

        // ---- P2: DMA h1 | read B(in2-3) | q01 (af held) ----
        async_ld16(sf + (size_t)128 * KTOT, db + 2 * 4096);
        async_ld16(sf + (size_t)192 * KTOT, db + 3 * 4096);
        #pragma unroll
        for (int in = 0; in < 2; ++in) {
            bf[in*2+0] = *(const short8*)(bB + ((in+2)*16)*BKT + sw0);
            bf[in*2+1] = *(const short8*)(bB + ((in+2)*16)*BKT + sw1);
        }
        __builtin_amdgcn_s_barrier();
        __builtin_amdgcn_s_setprio(1);
        #pragma unroll
        for (int im = 0; im < 4; ++im)
            #pragma unroll
            for (int in = 0; in < 2; ++in)
                #pragma unroll
                for (int kk = 0; kk < 2; ++kk)
                    acc[im][in+2] = __builtin_amdgcn_mfma_f32_16x16x32_bf16(
                        af[im*2+kk], bf[in*2+kk], acc[im][in+2], 0, 0, 0);
        __builtin_amdgcn_s_setprio(0);
        __builtin_amdgcn_s_barrier();

        // ---- P3: read A(im4-7) | q11 (bf held) ----
        #pragma unroll
        for (int im = 0; im < 4; ++im) {
            af[im*2+0] = *(const short8*)(aB + ((im+4)*16)*BKT + sw0);
            af[im*2+1] = *(const short8*)(aB + ((im+4)*16)*BKT + sw1);
        }
        __builtin_amdgcn_s_barrier();
        __builtin_amdgcn_s_setprio(1);
        #pragma unroll
        for (int im = 0; im < 4; ++im)
            #pragma unroll
            for (int in = 0; in < 2; ++in)
                #pragma unroll
                for (int kk = 0; kk < 2; ++kk)
                    acc[im+4][in+2] = __builtin_amdgcn_mfma_f32_16x16x32_bf16(
                        af[im*2+kk], bf[in*2+kk], acc[im+4][in+2], 0, 0, 0);
        __builtin_amdgcn_s_setprio(0);
        __builtin_amdgcn_s_barrier();

        // ---- P4: read B(in0-1) | build A(it+1) | counted vmcnt | q10 ----
        #pragma unroll
        for (int in = 0; in < 2; ++in) {
            bf[in*2+0] = *(const short8*)(bB + (in*16)*BKT + sw0);
            bf[in*2+1] = *(const short8*)(bB + (in*16)*BKT + sw1);
        }
        if (it + 1 < it1) buildA(it + 1);       // uniform branch
        // all but this iter's 2 newest VMEM ops done => B(it+1) fully landed
        asm volatile("s_waitcnt vmcnt(2)" ::: "memory");
        __builtin_amdgcn_s_barrier();
        __builtin_amdgcn_s_setprio(1);
        #pragma unroll
        for (int im = 0; im < 4; ++im)
            #pragma unroll
            for (int in = 0; in < 2; ++in)
                #pragma unroll
                for (int kk = 0; kk < 2; ++kk)
                    acc[im+4][in] = __builtin_amdgcn_mfma_f32_16x16x32_bf16(
                        af[im*2+kk], bf[in*2+kk], acc[im+4][in], 0, 0, 0);
        __builtin_amdgcn_s_setprio(0);
        // drain A-build ds_writes before next tile's A-reads cross the barrier
        asm volatile("s_waitcnt lgkmcnt(0)" ::: "memory");
        __builtin_amdgcn_s_barrier();

        pr = (pr == 2) ? 0 : pr + 1;
        ps = (ps == 2) ? 0 : ps + 1;
    }

    // epilogue: C/D map col=lane&15, row=quad*4+reg (m89-verified); atomic split-K
    #pragma unroll
    for (int im = 0; im < 8; ++im)
        #pragma unroll
        for (int in = 0; in < 4; ++in) {
            const int row = bm + wr * 128 + im * 16 + quad * 4;
            const int col = bn + wc * 64 + in * 16 + ml;
            #pragma unroll
            for (int rr = 0; rr < 4; ++rr)
                atomicAdd(&C[(size_t)(row + rr) * DOUT + col], acc[im][in][rr]);
        }
}

// ---------------------------------------------------------------------------
extern "C" void kernel_launch(void* const* d_in, const int* in_sizes, int n_in,
                              void* d_out, int out_size, void* d_ws, size_t ws_size,
                              hipStream_t stream) {
    const float* x  = (const float*)d_in[0];   // [4096,1024]
    const float* gw = (const float*)d_in[1];   // [1024,32]
    const float* gb = (const float*)d_in[2];   // [32]
    const float* pw = (const float*)d_in[3];   // [1024,1024,32]
    const float* pb = (const float*)d_in[4];   // [1024,32]
    float* out = (float*)d_out;                // [4096,1024]

    float* g            = (float*)d_ws;                               // 512 KB
    unsigned short* pwb = (unsigned short*)((char*)d_ws + (1 << 20)); // 67.2 MB

    prep_fused<<<DOUT + NB / 4 + 64, 256, 0, stream>>>(x, gw, gb, pw, pb, g, pwb, out);
    gemm_8phase<<<(DOUT / 256) * (NB / 256) * NSPLIT, 512, 0, stream>>>(x, g, pwb, out);
}

// Round 2
// 426.959 us; speedup vs baseline: 1.0435x; 1.0435x over previous
//
#include <hip/hip_runtime.h>
#include <stdint.h>

#define NB   4096
#define DIN  1024
#define DOUT 1024
#define NL   32
#define KPW  (DIN * NL)     // 32768
#define KTOT (KPW + 64)     // 32832 (pad: 32 bias cols + 32 zero cols)
#define BKT  64
#define NSPLIT 4            // split-K ways over 513 K-tiles: 129+128+128+128

typedef __attribute__((ext_vector_type(8))) short short8;          // 8 bf16 (A/B frag)
typedef __attribute__((ext_vector_type(8))) unsigned short ushort8;
typedef __attribute__((ext_vector_type(4))) float floatx4;         // C/D frag

// float -> bf16 bits, round-to-nearest-even (finite inputs only)
__device__ __forceinline__ unsigned short f2bf(float v) {
    uint32_t u = __float_as_uint(v);
    return (unsigned short)((u + 0x7FFFu + ((u >> 16) & 1u)) >> 16);
}

// two floats -> packed bf16x2 (RNE), low half = a (proven numerics, keep)
__device__ __forceinline__ uint32_t f2bf2(float a, float b) {
    uint32_t ua = __float_as_uint(a), ub = __float_as_uint(b);
    ua += 0x7FFFu + ((ua >> 16) & 1u);
    ub += 0x7FFFu + ((ub >> 16) & 1u);
    return __builtin_amdgcn_perm(ub, ua, 0x07060302u);  // {ub_hi16, ua_hi16}
}

// async global->LDS, 16B per lane; LDS dst = wave-uniform base + lane*16
__device__ __forceinline__ void async_ld16(const void* g, void* l) {
    __builtin_amdgcn_global_load_lds(
        (const __attribute__((address_space(1))) void*)g,
        (__attribute__((address_space(3))) void*)l, 16, 0, 0);
}

// ---------------------------------------------------------------------------
// Fused prep (unchanged; ~44us, near its HBM roofline):
//   blocks [0,1024)    : pw fp32 (+pb) -> bf16 pwb row
//   blocks [1024,2048) : gating softmax, 4 rows/block -> g fp32
//   blocks [2048,2112) : zero d_out (harness poisons it 0xAA each replay)
// ---------------------------------------------------------------------------
__global__ __launch_bounds__(256) void prep_fused(
    const float* __restrict__ x, const float* __restrict__ gw,
    const float* __restrict__ gb, const float* __restrict__ pw,
    const float* __restrict__ pb, float* __restrict__ g,
    unsigned short* __restrict__ pwb, float* __restrict__ C)
{
    const int id = blockIdx.x;
    const int t  = threadIdx.x;

    if (id < DOUT) {
        const int o = id;
        const float* src = pw + (size_t)o * KPW;
        unsigned short* dst = pwb + (size_t)o * KTOT;
        #pragma unroll 2
        for (int s = 0; s < 16; ++s) {
            const int k = (s * 256 + t) * 8;
            const float4 a = *(const float4*)(src + k);
            const float4 c = *(const float4*)(src + k + 4);
            ushort8 o8;
            o8[0] = f2bf(a.x); o8[1] = f2bf(a.y); o8[2] = f2bf(a.z); o8[3] = f2bf(a.w);
            o8[4] = f2bf(c.x); o8[5] = f2bf(c.y); o8[6] = f2bf(c.z); o8[7] = f2bf(c.w);
            *(ushort8*)(dst + k) = o8;
        }
        if (t < 8) {   // tail: 32 bias cols + 32 zeros
            ushort8 o8;
            #pragma unroll
            for (int j = 0; j < 8; ++j) {
                const int l = t * 8 + j;
                o8[j] = (l < NL) ? f2bf(pb[(size_t)o * NL + l]) : (unsigned short)0;
            }
            *(ushort8*)(dst + KPW + t * 8) = o8;
        }
    } else if (id < DOUT + NB / 4) {
        const int wave = t >> 6;
        const int lane = t & 63;
        const int b = (id - DOUT) * 4 + wave;
        const int l = lane & 31;
        const int c = lane >> 5;
        const float* xrow = x + (size_t)b * DIN;
        float p0 = 0.f, p1 = 0.f, p2 = 0.f, p3 = 0.f;
        const int i0 = c * 512;
        #pragma unroll 2
        for (int j = 0; j < 512; j += 4) {
            const int i = i0 + j;
            p0 = fmaf(xrow[i + 0], gw[(i + 0) * NL + l], p0);
            p1 = fmaf(xrow[i + 1], gw[(i + 1) * NL + l], p1);
            p2 = fmaf(xrow[i + 2], gw[(i + 2) * NL + l], p2);
            p3 = fmaf(xrow[i + 3], gw[(i + 3) * NL + l], p3);
        }
        float p = (p0 + p1) + (p2 + p3);
        p += __shfl_xor(p, 32);
        const float logit = p + gb[l];
        float m = logit;
        for (int off = 16; off > 0; off >>= 1) m = fmaxf(m, __shfl_xor(m, off));
        const float e = __expf(logit - m);
        float s = e;
        for (int off = 16; off > 0; off >>= 1) s += __shfl_xor(s, off);
        if (lane < NL) g[(size_t)b * NL + l] = e / s;
    } else {
        const int zb = id - (DOUT + NB / 4);
        float4* dst = (float4*)C + (size_t)zb * (256 * 64) + t;
        const float4 z4 = {0.f, 0.f, 0.f, 0.f};
        #pragma unroll 4
        for (int s = 0; s < 64; ++s) dst[s * 256] = z4;
    }
}

// ---------------------------------------------------------------------------
// r8: derived-waits rework of the 256x256 8-wave 4-phase GEMM (r7 post-mortem:
// the xv load inside the iteration forced a vmcnt(2) drain of same-iteration
// DMAs -> <1-tile pipeline depth; single-buffered A pinned the build into P4).
//  - A AND B double-buffered (2 x 32KB each = 128KB): build(it+1) goes to the
//    shadow A buffer in P2/P3, no reader-ordering constraint.
//  - All 4 B-DMAs for tile it+1 issue at P1-start; per-iter VMEM order is
//    [dma x4, xv_next] so the correctness wait is vmcnt(1) at P4 (B landed,
//    xv_next still in flight) -- never a full drain in the loop.
//  - x pipeline is 2-deep in registers: buildA(it+1) uses xv_cur loaded LAST
//    iteration, so its implicit wait is vmcnt(5): all 4 current DMAs stay
//    in flight (this was r7's killer).
//  - lgkmcnt(0) after q10 drains this wave's A-writes before the iter-end
//    barrier; lgkmcnt(8) pacing hint after P1's 12 ds_reads (template).
//  - Phases: P1{4 DMA | xv_next | 8A+4B reads | q00}  P2{4B reads | build
//    half-0 | q01}  P3{8A reads | build half-1 | q11}  P4{4B reads |
//    vmcnt(1) | q10 | lgkmcnt(0)}; quadrant order q00,q01,q11,q10 carries
//    af/bf across adjacent phases.
// ---------------------------------------------------------------------------
__global__ __launch_bounds__(512, 2) void gemm_8phase(
    const float* __restrict__ X,            // x [NB][DIN] fp32
    const float* __restrict__ G,            // g [NB][NL]  fp32
    const unsigned short* __restrict__ Bw,  // pwb [DOUT][KTOT] bf16
    float* __restrict__ C)                  // [NB][DOUT], pre-zeroed
{
    __shared__ __align__(16) unsigned short Ash[2][256 * BKT];  // 64 KB
    __shared__ __align__(16) unsigned short Bsh[2][256 * BKT];  // 64 KB

    const int t    = threadIdx.x;
    const int wave = t >> 6;
    const int lane = t & 63;

    // grid decode: XCD x gets combos {x, x+8} -> one bn panel, two z-windows
    const int bid   = blockIdx.x;
    const int xcd   = bid & 7;
    const int seq   = bid >> 3;                 // 0..31
    const int combo = xcd + 8 * (seq >> 4);     // 0..15 = (bn,z)
    const int bm    = (seq & 15) * 256;
    const int bn    = (combo & 3) * 256;
    const int z     = combo >> 2;               // 0..3
    const int it0   = z * 128 + (z ? 1 : 0);    // splits: 129+128+128+128
    const int it1   = (z + 1) * 128 + 1;

    // wave -> 128x64 output sub-tile
    const int wr   = wave >> 2;                 // 0..1
    const int wc   = wave & 3;                  // 0..3
    const int ml   = lane & 15;
    const int quad = lane >> 4;
    const int xm   = ml & 7;
    const int sw0  = (quad ^ xm) * 8;           // kk=0 chunk swizzle
    const int sw1  = ((4 + quad) ^ xm) * 8;     // kk=1

    // B staging: thread t stages row trow of each 64-row group, pre-swizzled src
    const int trow = t >> 3;                    // 0..63
    const unsigned short* Bg = Bw + (size_t)(bn + trow) * KTOT
                             + (((t & 7) ^ (trow & 7)) * 8);
    const int lbase = wave * 512;               // wave-uniform LDS stage base

    // A on-the-fly build: thread owns row r, leaves (t&1)*16..+15
    const int r = t >> 1, rx = r & 7, lsel = (t & 1) * 2;
    const float* xp = X + (size_t)(bm + r) * DIN;

    float gq[16];
    {
        const float* gp = G + (size_t)(bm + r) * NL + (t & 1) * 16;
        #pragma unroll
        for (int q = 0; q < 4; ++q) {
            const float4 v = *(const float4*)(gp + q * 4);
            gq[q*4+0] = v.x; gq[q*4+1] = v.y; gq[q*4+2] = v.z; gq[q*4+3] = v.w;
        }
    }

    floatx4 acc[8][4] = {};
    short8 af[8], bf[4];

    // build one half (ii = 0 uses xa-scale, ii = 1 uses xb-scale): 2 ds_writes
    auto buildHalf = [&](unsigned short* Adst, float xs, int ii) {
        #pragma unroll
        for (int j = 0; j < 2; ++j) {
            uint4 v;
            v.x = f2bf2(xs * gq[j*8+0], xs * gq[j*8+1]);
            v.y = f2bf2(xs * gq[j*8+2], xs * gq[j*8+3]);
            v.z = f2bf2(xs * gq[j*8+4], xs * gq[j*8+5]);
            v.w = f2bf2(xs * gq[j*8+6], xs * gq[j*8+7]);
            const int c = ii * 4 + lsel + j;
            *(uint4*)(Adst + ((c ^ rx) * 8)) = v;
        }
    };

    // ---- prologue: B(it0)->Bsh[0], A(it0)->Ash[0]; xv_cur = x for it0+1 ----
    float2 xq = *(const float2*)(xp + it0 * 2);          // x for tile it0
    {
        const unsigned short* s0 = Bg + (size_t)it0 * BKT;
        #pragma unroll
        for (int s = 0; s < 4; ++s)
            async_ld16(s0 + (size_t)s * 64 * KTOT, &Bsh[0][lbase + s * 4096]);
    }
    float2 xv_cur = *(const float2*)(xp + (it0 + 1) * 2); // x for tile it0+1
    {
        unsigned short* Adst = &Ash[0][r * BKT];
        buildHalf(Adst, xq.x, 0);
        buildHalf(Adst, xq.y, 1);
    }
    asm volatile("s_waitcnt vmcnt(0) lgkmcnt(0)" ::: "memory");
    __builtin_amdgcn_s_barrier();

    int cur = 0;
    for (int it = it0; it < it1; ++it) {
        const unsigned short* aB = &Ash[cur][(wr * 128 + ml) * BKT];
        const unsigned short* bB = &Bsh[cur][(wc * 64 + ml) * BKT];
        unsigned short* Adst = &Ash[cur ^ 1][r * BKT];
        unsigned short* db   = &Bsh[cur ^ 1][lbase];
        const int tf = (it + 1 < it1) ? (it + 1) : (it1 - 1); // dummy at tail
        const unsigned short* sf = Bg + (size_t)tf * BKT;

        // ---- P1: 4 B-DMAs(it+1) | xv_next | read A(im0-3)+B(in0-1) | q00 ----
        #pragma unroll
        for (int s = 0; s < 4; ++s)
            async_ld16(sf + (size_t)(s * 64) * KTOT, db + s * 4096);
        const int xi = (it + 2) * 2;
        float2 xv_next = *(const float2*)(xp + ((xi < DIN) ? xi : (DIN - 2)));
        #pragma unroll
        for (int im = 0; im < 4; ++im) {
            af[im*2+0] = *(const short8*)(aB + (im*16)*BKT + sw0);
            af[im*2+1] = *(const short8*)(aB + (im*16)*BKT + sw1);
        }
        #pragma unroll
        for (int in = 0; in < 2; ++in) {
            bf[in*2+0] = *(const short8*)(bB + (in*16)*BKT + sw0);
            bf[in*2+1] = *(const short8*)(bB + (in*16)*BKT + sw1);
        }
        asm volatile("s_waitcnt lgkmcnt(8)");   // pacing hint (12 reads issued)
        __builtin_amdgcn_s_barrier();
        __builtin_amdgcn_s_setprio(1);
        #pragma unroll
        for (int im = 0; im < 4; ++im)
            #pragma unroll
            for (int in = 0; in < 2; ++in)
                #pragma unroll
                for (int kk = 0; kk < 2; ++kk)
                    acc[im][in] = __builtin_amdgcn_mfma_f32_16x16x32_bf16(
                        af[im*2+kk], bf[in*2+kk], acc[im][in], 0, 0, 0);
        __builtin_amdgcn_s_setprio(0);
        __builtin_amdgcn_s_barrier();

        // ---- P2: read B(in2-3) | build half-0 of A(it+1) | q01 (af held) ----
        {
            const bool inb = ((it + 1) * 2) < DIN;
            const float xa = inb ? xv_cur.x : 1.0f;   // i=1024: y-col = g
            #pragma unroll
            for (int in = 0; in < 2; ++in) {
                bf[in*2+0] = *(const short8*)(bB + ((in+2)*16)*BKT + sw0);
                bf[in*2+1] = *(const short8*)(bB + ((in+2)*16)*BKT + sw1);
            }
            buildHalf(Adst, xa, 0);
        }
        __builtin_amdgcn_s_barrier();
        __builtin_amdgcn_s_setprio(1);
        #pragma unroll
        for (int im = 0; im < 4; ++im)
            #pragma unroll
            for (int in = 0; in < 2; ++in)
                #pragma unroll
                for (int kk = 0; kk < 2; ++kk)
                    acc[im][in+2] = __builtin_amdgcn_mfma_f32_16x16x32_bf16(
                        af[im*2+kk], bf[in*2+kk], acc[im][in+2], 0, 0, 0);
        __builtin_amdgcn_s_setprio(0);
        __builtin_amdgcn_s_barrier();

        // ---- P3: read A(im4-7) | build half-1 of A(it+1) | q11 (bf held) ----
        {
            const bool inb = ((it + 1) * 2) < DIN;
            const float xb = inb ? xv_cur.y : 0.0f;   // i=1025: zero pad
            #pragma unroll
            for (int im = 0; im < 4; ++im) {
                af[im*2+0] = *(const short8*)(aB + ((im+4)*16)*BKT + sw0);
                af[im*2+1] = *(const short8*)(aB + ((im+4)*16)*BKT + sw1);
            }
            buildHalf(Adst, xb, 1);
        }
        __builtin_amdgcn_s_barrier();
        __builtin_amdgcn_s_setprio(1);
        #pragma unroll
        for (int im = 0; im < 4; ++im)
            #pragma unroll
            for (int in = 0; in < 2; ++in)
                #pragma unroll
                for (int kk = 0; kk < 2; ++kk)
                    acc[im+4][in+2] = __builtin_amdgcn_mfma_f32_16x16x32_bf16(
                        af[im*2+kk], bf[in*2+kk], acc[im+4][in+2], 0, 0, 0);
        __builtin_amdgcn_s_setprio(0);
        __builtin_amdgcn_s_barrier();

        // ---- P4: read B(in0-1) | vmcnt(1): B(it+1) landed | q10 | lgkm(0) ----
        #pragma unroll
        for (int in = 0; in < 2; ++in) {
            bf[in*2+0] = *(const short8*)(bB + (in*16)*BKT + sw0);
            bf[in*2+1] = *(const short8*)(bB + (in*16)*BKT + sw1);
        }
        // drain this iter's 4 B-DMAs (xv_next, newer, stays in flight)
        asm volatile("s_waitcnt vmcnt(1)" ::: "memory");
        __builtin_amdgcn_s_barrier();
        __builtin_amdgcn_s_setprio(1);
        #pragma unroll
        for (int im = 0; im < 4; ++im)
            #pragma unroll
            for (int in = 0; in < 2; ++in)
                #pragma unroll
                for (int kk = 0; kk < 2; ++kk)
                    acc[im+4][in] = __builtin_amdgcn_mfma_f32_16x16x32_bf16(
                        af[im*2+kk], bf[in*2+kk], acc[im+4][in], 0, 0, 0);
        __builtin_amdgcn_s_setprio(0);
        // drain this wave's A-build ds_writes before next iter's A-reads
        asm volatile("s_waitcnt lgkmcnt(0)" ::: "memory");
        __builtin_amdgcn_s_barrier();

        xv_cur = xv_next;
        cur ^= 1;
    }

    // epilogue: C/D map col=lane&15, row=quad*4+reg (m89-verified); atomic split-K
    #pragma unroll
    for (int im = 0; im < 8; ++im)
        #pragma unroll
        for (int in = 0; in < 4; ++in) {
            const int row = bm + wr * 128 + im * 16 + quad * 4;
            const int col = bn + wc * 64 + in * 16 + ml;
            #pragma unroll
            for (int rr = 0; rr < 4; ++rr)
                atomicAdd(&C[(size_t)(row + rr) * DOUT + col], acc[im][in][rr]);
        }
}

// ---------------------------------------------------------------------------
extern "C" void kernel_launch(void* const* d_in, const int* in_sizes, int n_in,
                              void* d_out, int out_size, void* d_ws, size_t ws_size,
                              hipStream_t stream) {
    const float* x  = (const float*)d_in[0];   // [4096,1024]
    const float* gw = (const float*)d_in[1];   // [1024,32]
    const float* gb = (const float*)d_in[2];   // [32]
    const float* pw = (const float*)d_in[3];   // [1024,1024,32]
    const float* pb = (const float*)d_in[4];   // [1024,32]
    float* out = (float*)d_out;                // [4096,1024]

    float* g            = (float*)d_ws;                               // 512 KB
    unsigned short* pwb = (unsigned short*)((char*)d_ws + (1 << 20)); // 67.2 MB

    prep_fused<<<DOUT + NB / 4 + 64, 256, 0, stream>>>(x, gw, gb, pw, pb, g, pwb, out);
    gemm_8phase<<<(DOUT / 256) * (NB / 256) * NSPLIT, 512, 0, stream>>>(x, g, pwb, out);
}